// Round 1
// baseline (2439.099 us; speedup 1.0000x reference)
//
#include <hip/hip_runtime.h>
#include <hip/hip_bf16.h>
#include <stdint.h>

// ---------------- problem constants ----------------
#define B_    2
#define S_    4096
#define D_    2048
#define F_    8192
#define L_    2
#define FQ    (F_ / 4)         // 2048: F processed in quarters to cap workspace
#define NTOK  (B_ * S_)        // 8192 tokens
#define RCAP  (NTOK + 128)     // 8320 rows: 128-row zero gap between level0 (bottom-up) and level1 (top-down)
#define EPS_  1e-6f

// MFMA fragment types — guide-verified forms (ext_vector_type of short for bf16)
typedef __attribute__((ext_vector_type(8))) short s16x8;   // 8 bf16 in 4 VGPRs
typedef __attribute__((ext_vector_type(4))) float f32x4;   // 4 fp32 acc

typedef unsigned short u16;
typedef unsigned int   u32;

// ---------------- workspace layout (bytes), peak ~101.8 MB ----------------
// counts: [0]=level0 counter, [16]=level1 counter (separate cachelines to cut
// same-line atomic ping-pong across XCDs)
#define OFF_CNT   ((size_t)0)          // int[32] padded counters
#define OFF_ZL    ((size_t)128)        // float[64] sharded z-loss accum
#define OFF_MAP   ((size_t)384)        // int[RCAP]           -> ends 33664
#define OFF_WROW  ((size_t)33664)      // float[RCAP]         -> ends 66944
#define OFF_WTOK  ((size_t)66944)      // float[NTOK]         -> ends 99712
#define OFF_XG    ((size_t)99712)      // bf16[RCAP][D_]  (34.1 MB) -> ends 34178432
#define OFF_HQ    ((size_t)34178432)   // bf16[RCAP][FQ]  (34.1 MB) -> ends 68257152
#define OFF_WA    ((size_t)68257152)   // bf16 L*FQ*D_ (16 MB): WgT quarter, then WdT quarter
#define OFF_WB    ((size_t)85034368)   // bf16 L*FQ*D_ (16 MB): WuT quarter
// end = 101,811,584 B

__device__ __forceinline__ u16 f2bf(float f) {
    u32 u = __builtin_bit_cast(u32, f);
    u += 0x7fff + ((u >> 16) & 1);      // RNE
    return (u16)(u >> 16);
}

// async global->LDS, 16B per lane. lds ptr must be wave-uniform (HW writes
// base + lane*16); global ptr is per-lane. [guide m97/m104]
__device__ __forceinline__ void gl16(const u16* g, u16* l) {
    __builtin_amdgcn_global_load_lds(
        (const __attribute__((address_space(1))) void*)g,
        (__attribute__((address_space(3))) void*)l, 16, 0, 0);
}

// ---------------- init ----------------
__global__ void k_init(int* counts, float* zacc) {
    if (threadIdx.x == 0) { counts[0] = 0; counts[16] = 0; }
    zacc[threadIdx.x & 63] = 0.f;
}

// ---------------- router + rmsnorm + gather (one block per token) ----------------
__global__ __launch_bounds__(256) void k_router(
    const float* __restrict__ hs, const float* __restrict__ rw,
    const float* __restrict__ nw, int* __restrict__ counts,
    float* __restrict__ zacc, int* __restrict__ tmap,
    float* __restrict__ wrow, float* __restrict__ wtok, u16* __restrict__ Xg)
{
    int t = blockIdx.x;
    int tid = threadIdx.x;
    const float* x = hs + (size_t)t * D_;
    float xs[8];
    float sxx = 0.f, s0 = 0.f, s1 = 0.f;
#pragma unroll
    for (int i = 0; i < 8; i++) {
        int d = tid + i * 256;
        float v = x[d];
        xs[i] = v;
        sxx += v * v;
        s0  += v * rw[d];
        s1  += v * rw[D_ + d];
    }
#pragma unroll
    for (int off = 32; off; off >>= 1) {
        sxx += __shfl_down(sxx, off, 64);
        s0  += __shfl_down(s0,  off, 64);
        s1  += __shfl_down(s1,  off, 64);
    }
    __shared__ float red[3][4];
    __shared__ float bcf[1];
    __shared__ int   bci[2];
    int wave = tid >> 6, lane = tid & 63;
    if (lane == 0) { red[0][wave] = sxx; red[1][wave] = s0; red[2][wave] = s1; }
    __syncthreads();
    if (tid == 0) {
        sxx = red[0][0] + red[0][1] + red[0][2] + red[0][3];
        s0  = red[1][0] + red[1][1] + red[1][2] + red[1][3];
        s1  = red[2][0] + red[2][1] + red[2][2] + red[2][3];
        float m  = fmaxf(s0, s1);
        float e0 = __expf(s0 - m), e1 = __expf(s1 - m);
        float Z  = e0 + e1;
        int   idx = (s1 > s0) ? 1 : 0;               // argmax, first-max on tie
        float p   = ((idx == 0) ? e0 : e1) / Z;      // ALPHA = 1
        float z   = m + __logf(Z);                   // logsumexp
        atomicAdd(&zacc[t & 63], z * z * (1.0f / NTOK));   // 64-way sharded
        int pos = atomicAdd(&counts[idx << 4], 1);
        int row = (idx == 0) ? pos : (RCAP - 1 - pos);
        tmap[row] = t;
        wrow[row] = p;
        wtok[t]   = p;
        bcf[0] = rsqrtf(sxx * (1.0f / D_) + EPS_);
        bci[0] = idx; bci[1] = row;
    }
    __syncthreads();
    float inv = bcf[0];
    int idx = bci[0], row = bci[1];
    u16* xr = Xg + (size_t)row * D_;
    const float* w = nw + (size_t)idx * D_;
#pragma unroll
    for (int i = 0; i < 8; i++) {
        int d = tid + i * 256;
        xr[d] = f2bf(xs[i] * inv * w[d]);
    }
}

// ---------------- zero the 128-row gap ----------------
__global__ __launch_bounds__(256) void k_gap(const int* counts, int* tmap, u16* Xg) {
    int row = counts[0] + blockIdx.x;     // 128 blocks, one 4KB row each
    uint4* p = (uint4*)(Xg + (size_t)row * D_);
    p[threadIdx.x] = make_uint4(0u, 0u, 0u, 0u);
    if (threadIdx.x == 0) tmap[row] = -1;
}

// ---------------- out init: out = (1+w)*hs ----------------
__global__ __launch_bounds__(256) void k_outinit(
    const float* __restrict__ hs, const float* __restrict__ wtok,
    float* __restrict__ out)
{
    int t = blockIdx.x;
    float c = 1.f + wtok[t];
    const float4* ip = (const float4*)(hs + (size_t)t * D_);
    float4* op = (float4*)(out + (size_t)t * D_);
#pragma unroll
    for (int i = 0; i < 2; i++) {
        float4 v = ip[threadIdx.x + i * 256];
        v.x *= c; v.y *= c; v.z *= c; v.w *= c;
        op[threadIdx.x + i * 256] = v;
    }
}

// ---------------- transpose + cast: fp32 in[L][R][C] sub-block (r0,c0,RL,CL)
//                   -> bf16 out[L][CL][RL] ----------------
__global__ __launch_bounds__(256) void k_transpose(
    const float* __restrict__ in, u16* __restrict__ out,
    int R, int C, int r0, int c0, int RL, int CL)
{
    __shared__ float tile[32][33];
    int lc0 = blockIdx.x * 32;   // local col
    int lr0 = blockIdx.y * 32;   // local row
    const float* ip = in + (size_t)blockIdx.z * (size_t)R * (size_t)C;
    u16* op = out + (size_t)blockIdx.z * (size_t)CL * (size_t)RL;
    int tx = threadIdx.x & 31, ty = threadIdx.x >> 5;  // 32 x 8
#pragma unroll
    for (int i = 0; i < 4; i++)
        tile[ty + i * 8][tx] = ip[(size_t)(r0 + lr0 + ty + i * 8) * C + (c0 + lc0 + tx)];
    __syncthreads();
#pragma unroll
    for (int i = 0; i < 4; i++)
        op[(size_t)(lc0 + ty + i * 8) * RL + lr0 + tx] = f2bf(tile[tx][ty + i * 8]);
}

// ---------------- GEMM1 (dual): Hq = silu(Xg@WgTq^T) * (Xg@WuTq^T), bf16 ----------------
// grid: x = FQ/128 (16), y = RCAP/128 (65); 256 threads = 4 waves (2x2), 64x64 per wave
// m97 structure: global_load_lds width=16 staging, single-buffered LDS, 2 barriers/K-step
__global__ __launch_bounds__(256) void k_gemm1(
    const u16* __restrict__ Xg, const u16* __restrict__ WgT,
    const u16* __restrict__ WuT, const int* __restrict__ counts,
    u16* __restrict__ Hq)
{
    int nt = blockIdx.x, mt = blockIdx.y;
    int count0 = counts[0];
    int level = (mt * 128 < count0) ? 0 : 1;   // '<': a tile starting at count0 holds only gap/L1 rows
    const u16* Bg = WgT + (size_t)level * FQ * D_;
    const u16* Bu = WuT + (size_t)level * FQ * D_;

    __shared__ __align__(16) u16 As[128 * 32], Bgs[128 * 32], Bus[128 * 32];  // 24 KiB

    int tid = threadIdx.x, lane = tid & 63, wave = tid >> 6;
    int wm = wave >> 1, wn = wave & 1;
    int quad = lane >> 4, ln = lane & 15;

    f32x4 accG[4][4] = {}, accU[4][4] = {};

    // per-lane global src (row = tid>>2, 16B col = tid&3); LDS dest is linear in tid
    const u16* ga = Xg + (size_t)(mt * 128 + (tid >> 2)) * D_ + (tid & 3) * 8;
    const u16* gg = Bg + (size_t)(nt * 128 + (tid >> 2)) * D_ + (tid & 3) * 8;
    const u16* gu = Bu + (size_t)(nt * 128 + (tid >> 2)) * D_ + (tid & 3) * 8;

    // wave-uniform LDS bases: lane l lands at base + l*16B
    u16* lA = As  + (size_t)wave * 512;   // 1024 B per wave-call = 512 u16
    u16* lG = Bgs + (size_t)wave * 512;
    u16* lU = Bus + (size_t)wave * 512;

    for (int k0 = 0; k0 < D_; k0 += 32) {
        __syncthreads();   // previous iteration's fragment reads complete
        gl16(ga + k0, lA);
        gl16(ga + (size_t)64 * D_ + k0, lA + 2048);
        gl16(gg + k0, lG);
        gl16(gg + (size_t)64 * D_ + k0, lG + 2048);
        gl16(gu + k0, lU);
        gl16(gu + (size_t)64 * D_ + k0, lU + 2048);
        __syncthreads();   // compiler drains vmcnt(0) here -> LDS writes visible
        s16x8 a[4], bg[4], bu[4];
#pragma unroll
        for (int i = 0; i < 4; i++) {
            a[i]  = *(const s16x8*)(As  + (wm * 64 + i * 16 + ln) * 32 + quad * 8);
            bg[i] = *(const s16x8*)(Bgs + (wn * 64 + i * 16 + ln) * 32 + quad * 8);
            bu[i] = *(const s16x8*)(Bus + (wn * 64 + i * 16 + ln) * 32 + quad * 8);
        }
#pragma unroll
        for (int mi = 0; mi < 4; mi++)
#pragma unroll
            for (int ni = 0; ni < 4; ni++) {
                accG[mi][ni] = __builtin_amdgcn_mfma_f32_16x16x32_bf16(a[mi], bg[ni], accG[mi][ni], 0, 0, 0);
                accU[mi][ni] = __builtin_amdgcn_mfma_f32_16x16x32_bf16(a[mi], bu[ni], accU[mi][ni], 0, 0, 0);
            }
    }

    int rowbase = mt * 128 + wm * 64;
    int colbase = nt * 128 + wn * 64;
#pragma unroll
    for (int mi = 0; mi < 4; mi++)
#pragma unroll
        for (int ni = 0; ni < 4; ni++)
#pragma unroll
            for (int r = 0; r < 4; r++) {
                float g = accG[mi][ni][r], u = accU[mi][ni][r];
                float h = g / (1.f + __expf(-g)) * u;    // silu(g)*u
                int row = rowbase + mi * 16 + quad * 4 + r;   // C/D map: col=lane&15, row=quad*4+reg
                int col = colbase + ni * 16 + ln;
                Hq[(size_t)row * FQ + col] = f2bf(h);
            }
}

// ---------------- GEMM2 partial: out[tok] += w * (Hq @ WdTq^T) ----------------
// grid: x = D_/128 (16), y = RCAP/128 (65)
__global__ __launch_bounds__(256) void k_gemm2(
    const u16* __restrict__ Hq, const u16* __restrict__ WdT,
    const int* __restrict__ counts, const int* __restrict__ tmap,
    const float* __restrict__ wrow, float* __restrict__ out)
{
    int nt = blockIdx.x, mt = blockIdx.y;
    int count0 = counts[0];
    int level = (mt * 128 < count0) ? 0 : 1;
    const u16* Bd = WdT + (size_t)level * D_ * FQ;

    __shared__ __align__(16) u16 As[128 * 32], Bs[128 * 32];
    __shared__ int   stok[128];
    __shared__ float sw[128];

    int tid = threadIdx.x, lane = tid & 63, wave = tid >> 6;
    int wm = wave >> 1, wn = wave & 1;
    int quad = lane >> 4, ln = lane & 15;

    if (tid < 128) { stok[tid] = tmap[mt * 128 + tid]; sw[tid] = wrow[mt * 128 + tid]; }

    f32x4 acc[4][4] = {};

    const u16* ga = Hq + (size_t)(mt * 128 + (tid >> 2)) * FQ + (tid & 3) * 8;
    const u16* gb = Bd + (size_t)(nt * 128 + (tid >> 2)) * FQ + (tid & 3) * 8;

    u16* lA = As + (size_t)wave * 512;
    u16* lB = Bs + (size_t)wave * 512;

    for (int k0 = 0; k0 < FQ; k0 += 32) {
        __syncthreads();
        gl16(ga + k0, lA);
        gl16(ga + (size_t)64 * FQ + k0, lA + 2048);
        gl16(gb + k0, lB);
        gl16(gb + (size_t)64 * FQ + k0, lB + 2048);
        __syncthreads();
        s16x8 a[4], b[4];
#pragma unroll
        for (int i = 0; i < 4; i++) {
            a[i] = *(const s16x8*)(As + (wm * 64 + i * 16 + ln) * 32 + quad * 8);
            b[i] = *(const s16x8*)(Bs + (wn * 64 + i * 16 + ln) * 32 + quad * 8);
        }
#pragma unroll
        for (int mi = 0; mi < 4; mi++)
#pragma unroll
            for (int ni = 0; ni < 4; ni++)
                acc[mi][ni] = __builtin_amdgcn_mfma_f32_16x16x32_bf16(a[mi], b[ni], acc[mi][ni], 0, 0, 0);
    }

    int colbase = nt * 128 + wn * 64;
#pragma unroll
    for (int mi = 0; mi < 4; mi++)
#pragma unroll
        for (int ni = 0; ni < 4; ni++)
#pragma unroll
            for (int r = 0; r < 4; r++) {
                int rl = wm * 64 + mi * 16 + quad * 4 + r;
                int tok = stok[rl];
                if (tok < 0) continue;
                float w = sw[rl];
                int col = colbase + ni * 16 + ln;
                size_t oidx = (size_t)tok * D_ + col;
                out[oidx] += w * acc[mi][ni][r];   // disjoint tiles per block; launches serialize
            }
}

// ---------------- z-loss write ----------------
__global__ void k_zout(const float* zacc, float* out) {
    float s = 0.f;
#pragma unroll
    for (int i = 0; i < 64; i++) s += zacc[i];
    out[(size_t)NTOK * D_] = s;
}

extern "C" void kernel_launch(void* const* d_in, const int* in_sizes, int n_in,
                              void* d_out, int out_size, void* d_ws, size_t ws_size,
                              hipStream_t stream) {
    const float* hs = (const float*)d_in[0];
    const float* rw = (const float*)d_in[1];
    const float* Wg = (const float*)d_in[2];
    const float* Wu = (const float*)d_in[3];
    const float* Wd = (const float*)d_in[4];
    const float* nw = (const float*)d_in[5];
    float* out = (float*)d_out;

    char* ws = (char*)d_ws;
    int*   counts = (int*)(ws + OFF_CNT);
    float* zacc   = (float*)(ws + OFF_ZL);
    int*   tmap   = (int*)(ws + OFF_MAP);
    float* wrow   = (float*)(ws + OFF_WROW);
    float* wtok   = (float*)(ws + OFF_WTOK);
    u16*   Xg     = (u16*)(ws + OFF_XG);
    u16*   Hq     = (u16*)(ws + OFF_HQ);
    u16*   WA     = (u16*)(ws + OFF_WA);   // WgT quarter, then WdT quarter
    u16*   WB     = (u16*)(ws + OFF_WB);   // WuT quarter

    k_init<<<1, 64, 0, stream>>>(counts, zacc);
    k_router<<<NTOK, 256, 0, stream>>>(hs, rw, nw, counts, zacc, tmap, wrow, wtok, Xg);
    k_gap<<<128, 256, 0, stream>>>(counts, tmap, Xg);
    k_outinit<<<NTOK, 256, 0, stream>>>(hs, wtok, out);

    for (int q = 0; q < 4; q++) {
        // Wg, Wu are [L][D][F]: transpose col-range [q*FQ, +FQ) -> [L][FQ][D]
        k_transpose<<<dim3(FQ / 32, D_ / 32, L_), 256, 0, stream>>>(Wg, WA, D_, F_, 0, q * FQ, D_, FQ);
        k_transpose<<<dim3(FQ / 32, D_ / 32, L_), 256, 0, stream>>>(Wu, WB, D_, F_, 0, q * FQ, D_, FQ);
        k_gemm1<<<dim3(FQ / 128, RCAP / 128), 256, 0, stream>>>(Xg, WA, WB, counts, Hq);
        // Wd is [L][F][D]: transpose row-range [q*FQ, +FQ) -> [L][D][FQ]  (reuses WA)
        k_transpose<<<dim3(D_ / 32, FQ / 32, L_), 256, 0, stream>>>(Wd, WA, F_, D_, q * FQ, 0, FQ, D_);
        k_gemm2<<<dim3(D_ / 128, RCAP / 128), 256, 0, stream>>>(Hq, WA, counts, tmap, wrow, out);
    }
    k_zout<<<1, 1, 0, stream>>>(zacc, out);
}

// Round 2
// 1830.402 us; speedup vs baseline: 1.3325x; 1.3325x over previous
//
#include <hip/hip_runtime.h>
#include <hip/hip_bf16.h>
#include <stdint.h>

// ---------------- problem constants ----------------
#define B_    2
#define S_    4096
#define D_    2048
#define F_    8192
#define L_    2
#define FQ    (F_ / 4)         // 2048: F processed in quarters to cap workspace
#define NTOK  (B_ * S_)        // 8192 tokens
#define RCAP  (NTOK + 128)     // 8320 rows: 128-row zero gap between level0 (bottom-up) and level1 (top-down)
#define EPS_  1e-6f

// MFMA fragment types — guide-verified forms (ext_vector_type of short for bf16)
typedef __attribute__((ext_vector_type(8))) short s16x8;   // 8 bf16 in 4 VGPRs
typedef __attribute__((ext_vector_type(4))) float f32x4;   // 4 fp32 acc

typedef unsigned short u16;
typedef unsigned int   u32;

// ---------------- workspace layout (bytes), peak ~101.8 MB ----------------
// counts: [0]=level0 counter, [16]=level1 counter (separate cachelines)
#define OFF_CNT   ((size_t)0)          // int[32] padded counters
#define OFF_ZL    ((size_t)128)        // float[64] sharded z-loss accum
#define OFF_MAP   ((size_t)384)        // int[RCAP]           -> ends 33664
#define OFF_WROW  ((size_t)33664)      // float[RCAP]         -> ends 66944
#define OFF_WTOK  ((size_t)66944)      // float[NTOK]         -> ends 99712
#define OFF_XG    ((size_t)99712)      // bf16[RCAP][D_]  (34.1 MB) -> ends 34178432
#define OFF_HQ    ((size_t)34178432)   // bf16[RCAP][FQ]  (34.1 MB) -> ends 68257152
#define OFF_WA    ((size_t)68257152)   // bf16 L*FQ*D_ (16 MB): WgT quarter, then WdT quarter
#define OFF_WB    ((size_t)85034368)   // bf16 L*FQ*D_ (16 MB): WuT quarter
// end = 101,811,584 B

__device__ __forceinline__ u16 f2bf(float f) {
    u32 u = __builtin_bit_cast(u32, f);
    u += 0x7fff + ((u >> 16) & 1);      // RNE
    return (u16)(u >> 16);
}

// async global->LDS, 16B per lane. lds ptr must be wave-uniform (HW writes
// base + lane*16); global ptr is per-lane. [guide m97/m104]
__device__ __forceinline__ void gl16(const u16* g, u16* l) {
    __builtin_amdgcn_global_load_lds(
        (const __attribute__((address_space(1))) void*)g,
        (__attribute__((address_space(3))) void*)l, 16, 0, 0);
}

// ---------------- init ----------------
__global__ void k_init(int* counts, float* zacc) {
    if (threadIdx.x == 0) { counts[0] = 0; counts[16] = 0; }
    zacc[threadIdx.x & 63] = 0.f;
}

// ---------------- router + rmsnorm + gather (one block per token) ----------------
__global__ __launch_bounds__(256) void k_router(
    const float* __restrict__ hs, const float* __restrict__ rw,
    const float* __restrict__ nw, int* __restrict__ counts,
    float* __restrict__ zacc, int* __restrict__ tmap,
    float* __restrict__ wrow, float* __restrict__ wtok, u16* __restrict__ Xg)
{
    int t = blockIdx.x;
    int tid = threadIdx.x;
    const float* x = hs + (size_t)t * D_;
    float xs[8];
    float sxx = 0.f, s0 = 0.f, s1 = 0.f;
#pragma unroll
    for (int i = 0; i < 8; i++) {
        int d = tid + i * 256;
        float v = x[d];
        xs[i] = v;
        sxx += v * v;
        s0  += v * rw[d];
        s1  += v * rw[D_ + d];
    }
#pragma unroll
    for (int off = 32; off; off >>= 1) {
        sxx += __shfl_down(sxx, off, 64);
        s0  += __shfl_down(s0,  off, 64);
        s1  += __shfl_down(s1,  off, 64);
    }
    __shared__ float red[3][4];
    __shared__ float bcf[1];
    __shared__ int   bci[2];
    int wave = tid >> 6, lane = tid & 63;
    if (lane == 0) { red[0][wave] = sxx; red[1][wave] = s0; red[2][wave] = s1; }
    __syncthreads();
    if (tid == 0) {
        sxx = red[0][0] + red[0][1] + red[0][2] + red[0][3];
        s0  = red[1][0] + red[1][1] + red[1][2] + red[1][3];
        s1  = red[2][0] + red[2][1] + red[2][2] + red[2][3];
        float m  = fmaxf(s0, s1);
        float e0 = __expf(s0 - m), e1 = __expf(s1 - m);
        float Z  = e0 + e1;
        int   idx = (s1 > s0) ? 1 : 0;               // argmax, first-max on tie
        float p   = ((idx == 0) ? e0 : e1) / Z;      // ALPHA = 1
        float z   = m + __logf(Z);                   // logsumexp
        atomicAdd(&zacc[t & 63], z * z * (1.0f / NTOK));   // 64-way sharded
        int pos = atomicAdd(&counts[idx << 4], 1);
        int row = (idx == 0) ? pos : (RCAP - 1 - pos);
        tmap[row] = t;
        wrow[row] = p;
        wtok[t]   = p;
        bcf[0] = rsqrtf(sxx * (1.0f / D_) + EPS_);
        bci[0] = idx; bci[1] = row;
    }
    __syncthreads();
    float inv = bcf[0];
    int idx = bci[0], row = bci[1];
    u16* xr = Xg + (size_t)row * D_;
    const float* w = nw + (size_t)idx * D_;
#pragma unroll
    for (int i = 0; i < 8; i++) {
        int d = tid + i * 256;
        xr[d] = f2bf(xs[i] * inv * w[d]);
    }
}

// ---------------- zero the 128-row gap ----------------
__global__ __launch_bounds__(256) void k_gap(const int* counts, int* tmap, u16* Xg) {
    int row = counts[0] + blockIdx.x;     // 128 blocks, one 4KB row each
    uint4* p = (uint4*)(Xg + (size_t)row * D_);
    p[threadIdx.x] = make_uint4(0u, 0u, 0u, 0u);
    if (threadIdx.x == 0) tmap[row] = -1;
}

// ---------------- out init: out = (1+w)*hs ----------------
__global__ __launch_bounds__(256) void k_outinit(
    const float* __restrict__ hs, const float* __restrict__ wtok,
    float* __restrict__ out)
{
    int t = blockIdx.x;
    float c = 1.f + wtok[t];
    const float4* ip = (const float4*)(hs + (size_t)t * D_);
    float4* op = (float4*)(out + (size_t)t * D_);
#pragma unroll
    for (int i = 0; i < 2; i++) {
        float4 v = ip[threadIdx.x + i * 256];
        v.x *= c; v.y *= c; v.z *= c; v.w *= c;
        op[threadIdx.x + i * 256] = v;
    }
}

// ---------------- transpose + cast: fp32 in[L][R][C] sub-block (r0,c0,RL,CL)
//                   -> bf16 out[L][CL][RL] ----------------
__global__ __launch_bounds__(256) void k_transpose(
    const float* __restrict__ in, u16* __restrict__ out,
    int R, int C, int r0, int c0, int RL, int CL)
{
    __shared__ float tile[32][33];
    int lc0 = blockIdx.x * 32;   // local col
    int lr0 = blockIdx.y * 32;   // local row
    const float* ip = in + (size_t)blockIdx.z * (size_t)R * (size_t)C;
    u16* op = out + (size_t)blockIdx.z * (size_t)CL * (size_t)RL;
    int tx = threadIdx.x & 31, ty = threadIdx.x >> 5;  // 32 x 8
#pragma unroll
    for (int i = 0; i < 4; i++)
        tile[ty + i * 8][tx] = ip[(size_t)(r0 + lr0 + ty + i * 8) * C + (c0 + lc0 + tx)];
    __syncthreads();
#pragma unroll
    for (int i = 0; i < 4; i++)
        op[(size_t)(lc0 + ty + i * 8) * RL + lr0 + tx] = f2bf(tile[tx][ty + i * 8]);
}

// ---------------- GEMM1 (dual): Hq = silu(Xg@WgTq^T) * (Xg@WuTq^T), bf16 ----------------
// grid: x = FQ/64 (32), y = RCAP/128 (65); 256 threads = 4 waves (2x2)
// Per-wave output 64x32 of BOTH G and U: accG[4][2]+accU[4][2] = 64 AGPR,
// ~174 combined regs/wave -> 2 waves/SIMD (vs 288 -> 1 wave/SIMD at 64x64 dual).
// [m69: per-SIMD reg pool = 512] Occupancy was the round-1 bottleneck
// (Occ 9.7%, MfmaUtil 16%).
__global__ __launch_bounds__(256, 2) void k_gemm1(
    const u16* __restrict__ Xg, const u16* __restrict__ WgT,
    const u16* __restrict__ WuT, const int* __restrict__ counts,
    u16* __restrict__ Hq)
{
    int nt = blockIdx.x, mt = blockIdx.y;
    int count0 = counts[0];
    int level = (mt * 128 < count0) ? 0 : 1;   // '<': a tile starting at count0 holds only gap/L1 rows
    const u16* Bg = WgT + (size_t)level * FQ * D_;
    const u16* Bu = WuT + (size_t)level * FQ * D_;

    __shared__ __align__(16) u16 As[128 * 32], Bgs[64 * 32], Bus[64 * 32];  // 16 KiB

    int tid = threadIdx.x, lane = tid & 63, wave = tid >> 6;
    int wm = wave >> 1, wn = wave & 1;
    int quad = lane >> 4, ln = lane & 15;

    f32x4 accG[4][2] = {}, accU[4][2] = {};

    // per-lane global src (row = tid>>2, 16B col = tid&3); LDS dest linear in tid
    const u16* ga = Xg + (size_t)(mt * 128 + (tid >> 2)) * D_ + (tid & 3) * 8;
    const u16* gg = Bg + (size_t)(nt * 64 + (tid >> 2)) * D_ + (tid & 3) * 8;
    const u16* gu = Bu + (size_t)(nt * 64 + (tid >> 2)) * D_ + (tid & 3) * 8;

    // wave-uniform LDS bases: lane l lands at base + l*16B
    u16* lA = As  + (size_t)wave * 512;   // 1 KiB per wave-call
    u16* lG = Bgs + (size_t)wave * 512;
    u16* lU = Bus + (size_t)wave * 512;

    for (int k0 = 0; k0 < D_; k0 += 32) {
        __syncthreads();   // previous iteration's fragment reads complete
        gl16(ga + k0, lA);
        gl16(ga + (size_t)64 * D_ + k0, lA + 2048);
        gl16(gg + k0, lG);             // 64x32 B tile = one 4KB call across 4 waves
        gl16(gu + k0, lU);
        __syncthreads();   // compiler drains vmcnt(0) here -> LDS writes visible
        s16x8 a[4], bg[2], bu[2];
#pragma unroll
        for (int i = 0; i < 4; i++)
            a[i]  = *(const s16x8*)(As  + (wm * 64 + i * 16 + ln) * 32 + quad * 8);
#pragma unroll
        for (int j = 0; j < 2; j++) {
            bg[j] = *(const s16x8*)(Bgs + (wn * 32 + j * 16 + ln) * 32 + quad * 8);
            bu[j] = *(const s16x8*)(Bus + (wn * 32 + j * 16 + ln) * 32 + quad * 8);
        }
#pragma unroll
        for (int mi = 0; mi < 4; mi++)
#pragma unroll
            for (int ni = 0; ni < 2; ni++) {
                accG[mi][ni] = __builtin_amdgcn_mfma_f32_16x16x32_bf16(a[mi], bg[ni], accG[mi][ni], 0, 0, 0);
                accU[mi][ni] = __builtin_amdgcn_mfma_f32_16x16x32_bf16(a[mi], bu[ni], accU[mi][ni], 0, 0, 0);
            }
    }

    int rowbase = mt * 128 + wm * 64;
    int colbase = nt * 64 + wn * 32;
#pragma unroll
    for (int mi = 0; mi < 4; mi++)
#pragma unroll
        for (int ni = 0; ni < 2; ni++)
#pragma unroll
            for (int r = 0; r < 4; r++) {
                float g = accG[mi][ni][r], u = accU[mi][ni][r];
                float h = g / (1.f + __expf(-g)) * u;    // silu(g)*u
                int row = rowbase + mi * 16 + quad * 4 + r;   // C/D map: col=lane&15, row=quad*4+reg
                int col = colbase + ni * 16 + ln;
                Hq[(size_t)row * FQ + col] = f2bf(h);
            }
}

// ---------------- GEMM2 partial: out[tok] += w * (Hq @ WdTq^T) ----------------
// grid: x = D_/128 (16), y = RCAP/128 (65)
__global__ __launch_bounds__(256, 2) void k_gemm2(
    const u16* __restrict__ Hq, const u16* __restrict__ WdT,
    const int* __restrict__ counts, const int* __restrict__ tmap,
    const float* __restrict__ wrow, float* __restrict__ out)
{
    int nt = blockIdx.x, mt = blockIdx.y;
    int count0 = counts[0];
    int level = (mt * 128 < count0) ? 0 : 1;
    const u16* Bd = WdT + (size_t)level * D_ * FQ;

    __shared__ __align__(16) u16 As[128 * 32], Bs[128 * 32];
    __shared__ int   stok[128];
    __shared__ float sw[128];

    int tid = threadIdx.x, lane = tid & 63, wave = tid >> 6;
    int wm = wave >> 1, wn = wave & 1;
    int quad = lane >> 4, ln = lane & 15;

    if (tid < 128) { stok[tid] = tmap[mt * 128 + tid]; sw[tid] = wrow[mt * 128 + tid]; }

    f32x4 acc[4][4] = {};

    const u16* ga = Hq + (size_t)(mt * 128 + (tid >> 2)) * FQ + (tid & 3) * 8;
    const u16* gb = Bd + (size_t)(nt * 128 + (tid >> 2)) * FQ + (tid & 3) * 8;

    u16* lA = As + (size_t)wave * 512;
    u16* lB = Bs + (size_t)wave * 512;

    for (int k0 = 0; k0 < FQ; k0 += 32) {
        __syncthreads();
        gl16(ga + k0, lA);
        gl16(ga + (size_t)64 * FQ + k0, lA + 2048);
        gl16(gb + k0, lB);
        gl16(gb + (size_t)64 * FQ + k0, lB + 2048);
        __syncthreads();
        s16x8 a[4], b[4];
#pragma unroll
        for (int i = 0; i < 4; i++) {
            a[i] = *(const s16x8*)(As + (wm * 64 + i * 16 + ln) * 32 + quad * 8);
            b[i] = *(const s16x8*)(Bs + (wn * 64 + i * 16 + ln) * 32 + quad * 8);
        }
#pragma unroll
        for (int mi = 0; mi < 4; mi++)
#pragma unroll
            for (int ni = 0; ni < 4; ni++)
                acc[mi][ni] = __builtin_amdgcn_mfma_f32_16x16x32_bf16(a[mi], b[ni], acc[mi][ni], 0, 0, 0);
    }

    int colbase = nt * 128 + wn * 64;
#pragma unroll
    for (int mi = 0; mi < 4; mi++)
#pragma unroll
        for (int ni = 0; ni < 4; ni++)
#pragma unroll
            for (int r = 0; r < 4; r++) {
                int rl = wm * 64 + mi * 16 + quad * 4 + r;
                int tok = stok[rl];
                if (tok < 0) continue;
                float w = sw[rl];
                int col = colbase + ni * 16 + ln;
                size_t oidx = (size_t)tok * D_ + col;
                out[oidx] += w * acc[mi][ni][r];   // disjoint tiles per block; launches serialize
            }
}

// ---------------- z-loss write ----------------
__global__ void k_zout(const float* zacc, float* out) {
    float s = 0.f;
#pragma unroll
    for (int i = 0; i < 64; i++) s += zacc[i];
    out[(size_t)NTOK * D_] = s;
}

extern "C" void kernel_launch(void* const* d_in, const int* in_sizes, int n_in,
                              void* d_out, int out_size, void* d_ws, size_t ws_size,
                              hipStream_t stream) {
    const float* hs = (const float*)d_in[0];
    const float* rw = (const float*)d_in[1];
    const float* Wg = (const float*)d_in[2];
    const float* Wu = (const float*)d_in[3];
    const float* Wd = (const float*)d_in[4];
    const float* nw = (const float*)d_in[5];
    float* out = (float*)d_out;

    char* ws = (char*)d_ws;
    int*   counts = (int*)(ws + OFF_CNT);
    float* zacc   = (float*)(ws + OFF_ZL);
    int*   tmap   = (int*)(ws + OFF_MAP);
    float* wrow   = (float*)(ws + OFF_WROW);
    float* wtok   = (float*)(ws + OFF_WTOK);
    u16*   Xg     = (u16*)(ws + OFF_XG);
    u16*   Hq     = (u16*)(ws + OFF_HQ);
    u16*   WA     = (u16*)(ws + OFF_WA);   // WgT quarter, then WdT quarter
    u16*   WB     = (u16*)(ws + OFF_WB);   // WuT quarter

    k_init<<<1, 64, 0, stream>>>(counts, zacc);
    k_router<<<NTOK, 256, 0, stream>>>(hs, rw, nw, counts, zacc, tmap, wrow, wtok, Xg);
    k_gap<<<128, 256, 0, stream>>>(counts, tmap, Xg);
    k_outinit<<<NTOK, 256, 0, stream>>>(hs, wtok, out);

    for (int q = 0; q < 4; q++) {
        // Wg, Wu are [L][D][F]: transpose col-range [q*FQ, +FQ) -> [L][FQ][D]
        k_transpose<<<dim3(FQ / 32, D_ / 32, L_), 256, 0, stream>>>(Wg, WA, D_, F_, 0, q * FQ, D_, FQ);
        k_transpose<<<dim3(FQ / 32, D_ / 32, L_), 256, 0, stream>>>(Wu, WB, D_, F_, 0, q * FQ, D_, FQ);
        k_gemm1<<<dim3(FQ / 64, RCAP / 128), 256, 0, stream>>>(Xg, WA, WB, counts, Hq);
        // Wd is [L][F][D]: transpose row-range [q*FQ, +FQ) -> [L][D][FQ]  (reuses WA)
        k_transpose<<<dim3(D_ / 32, FQ / 32, L_), 256, 0, stream>>>(Wd, WA, F_, D_, q * FQ, 0, FQ, D_);
        k_gemm2<<<dim3(D_ / 128, RCAP / 128), 256, 0, stream>>>(Hq, WA, counts, tmap, wrow, out);
    }
    k_zout<<<1, 1, 0, stream>>>(zacc, out);
}